// Round 14
// baseline (306.451 us; speedup 1.0000x reference)
//
#include <hip/hip_runtime.h>
#include <math.h>

// Problem constants
#define Bn 2
#define Sn 512
#define Hn 128
#define NHn 4
#define Dn 32
#define BAGn 5
#define NMETAn 16
#define ROWS 1024
#define NBn 2
#define Tt 257

#define NEGF (-4294967295.0f)
#define INV_SQRT_D 0.17677669529663687f
#define SQRT_H 11.313708498984761f
#define EPS_EMB 1e-5f
#define EPSF 1e-8f

// workspace float offsets
#define OFF_QN    0
#define OFF_Q     131072
#define OFF_K     262144
#define OFF_V     393216
#define OFF_O     524288

static __device__ __forceinline__ float red64(float v) {
#pragma unroll
    for (int m = 1; m < 64; m <<= 1) v += __shfl_xor(v, m, 64);
    return v;
}
static __device__ __forceinline__ float red64max(float v) {
#pragma unroll
    for (int m = 1; m < 64; m <<= 1) v = fmaxf(v, __shfl_xor(v, m, 64));
    return v;
}

// ===========================================================================
// Embed + embLN + keep + attnLN(0) + QKV(0), 2 rows/block (512 blocks).
// (unchanged from round 13)
// ===========================================================================
__global__ __launch_bounds__(256) void embed_qkv_kernel(
    const int* __restrict__ ids, const float* __restrict__ meta,
    const int* __restrict__ cats,
    const float* __restrict__ item_w, const float* __restrict__ cat_w,
    const float* __restrict__ numW, const float* __restrict__ numb,
    const float* __restrict__ fusW, const float* __restrict__ fusb,
    const float* __restrict__ elng, const float* __restrict__ elnb,
    const float* __restrict__ alng, const float* __restrict__ alnb,
    const float* __restrict__ QW, const float* __restrict__ Qb,
    const float* __restrict__ KW, const float* __restrict__ Kb,
    const float* __restrict__ VW, const float* __restrict__ Vb,
    const float* __restrict__ posK, const float* __restrict__ posV,
    float* __restrict__ Qn, float* __restrict__ Q,
    float* __restrict__ K, float* __restrict__ V)
{
    int r0 = blockIdx.x * 2, t = threadIdx.x;
    __shared__ float combs[512], xs[256], qs[256], parts[256], pk[256], pv[256];
    __shared__ float wsum[8];
    __shared__ int idl[2];
    if (t < 2) idl[t] = ids[r0 + t];
    __syncthreads();
    { int r = t >> 7, c = t & 127; combs[r * 256 + c] = item_w[idl[r] * Hn + c] * SQRT_H; }
    if (t < 128) {
        int r = t >> 6, c = t & 63;
        float acc = numb[c];
#pragma unroll
        for (int m2 = 0; m2 < NMETAn; ++m2)
            acc += meta[(r0 + r) * NMETAn + m2] * numW[c * NMETAn + m2];
        combs[r * 256 + 128 + c] = acc;
    } else {
        int u = t - 128, r = u >> 6, c = u & 63;
        float ca = 0.f; int cnt = 0;
#pragma unroll
        for (int k2 = 0; k2 < BAGn; ++k2) {
            int cc2 = cats[(r0 + r) * BAGn + k2];
            if (cc2 != 0) { ca += cat_w[cc2 * 64 + c]; cnt++; }
        }
        combs[r * 256 + 192 + c] = ca / (float)(cnt > 0 ? cnt : 1);
    }
    __syncthreads();
    int h = t & 127, kh = t >> 7;
    {
        const float4* w4p = (const float4*)(fusW + h * 256 + kh * 128);
        const float* c0 = combs + kh * 128;
        const float* c1 = combs + 256 + kh * 128;
        float a0 = 0.f, a1 = 0.f, b0 = 0.f, b1 = 0.f;
#pragma unroll 16
        for (int k4 = 0; k4 < 32; ++k4) {
            float4 w4 = w4p[k4];
            int k = k4 * 4;
            a0 += c0[k] * w4.x + c0[k + 1] * w4.y;
            a1 += c0[k + 2] * w4.z + c0[k + 3] * w4.w;
            b0 += c1[k] * w4.x + c1[k + 1] * w4.y;
            b1 += c1[k + 2] * w4.z + c1[k + 3] * w4.w;
        }
        float A0 = a0 + a1, A1 = b0 + b1;
        if (kh) { parts[h] = A0; parts[128 + h] = A1; }
        __syncthreads();
        if (!kh) {
            xs[h] = A0 + parts[h] + fusb[h];
            xs[128 + h] = A1 + parts[128 + h] + fusb[h];
        }
    }
    __syncthreads();
    int w_ = t >> 6, row = w_ >> 1, l = t & 63, ch = ((w_ & 1) << 6) + l;
    float x = xs[row * 128 + ch];
    float s1 = red64(x);
    if (l == 0) wsum[w_] = s1;
    __syncthreads();
    float mean = (wsum[row * 2] + wsum[row * 2 + 1]) * (1.f / 128.f);
    float dlt = x - mean;
    float s2 = red64(dlt * dlt);
    if (l == 0) wsum[4 + w_] = s2;
    __syncthreads();
    float rstd = rsqrtf((wsum[4 + row * 2] + wsum[4 + row * 2 + 1]) * (1.f / 128.f) + EPS_EMB);
    float xv = dlt * rstd * elng[ch] + elnb[ch];
    xv = (idl[row] == 0) ? 0.f : xv;
    __syncthreads();
    xs[row * 128 + ch] = xv;
    __syncthreads();
    s1 = red64(xv);
    if (l == 0) wsum[w_] = s1;
    __syncthreads();
    mean = (wsum[row * 2] + wsum[row * 2 + 1]) * (1.f / 128.f);
    dlt = xv - mean;
    s2 = red64(dlt * dlt);
    if (l == 0) wsum[4 + w_] = s2;
    __syncthreads();
    rstd = rsqrtf((wsum[4 + row * 2] + wsum[4 + row * 2 + 1]) * (1.f / 128.f) + EPSF);
    float qn = dlt * rstd * alng[ch] + alnb[ch];
    qs[row * 128 + ch] = qn;
    Qn[(r0 + row) * 128 + ch] = qn;
    __syncthreads();
    {
        const float4* qw4 = (const float4*)(QW + h * 128 + kh * 64);
        const float4* kw4 = (const float4*)(KW + h * 128 + kh * 64);
        const float4* vw4 = (const float4*)(VW + h * 128 + kh * 64);
        const float* q0p = qs + kh * 64;
        const float* q1p = qs + 128 + kh * 64;
        const float* x0p = xs + kh * 64;
        const float* x1p = xs + 128 + kh * 64;
        float aq0 = 0, aq1 = 0, ak0 = 0, ak1 = 0, av0 = 0, av1 = 0;
#pragma unroll 8
        for (int k4 = 0; k4 < 16; ++k4) {
            float4 wq = qw4[k4], wk = kw4[k4], wv = vw4[k4];
            int k = k4 * 4;
            aq0 += q0p[k] * wq.x + q0p[k + 1] * wq.y + q0p[k + 2] * wq.z + q0p[k + 3] * wq.w;
            aq1 += q1p[k] * wq.x + q1p[k + 1] * wq.y + q1p[k + 2] * wq.z + q1p[k + 3] * wq.w;
            ak0 += x0p[k] * wk.x + x0p[k + 1] * wk.y + x0p[k + 2] * wk.z + x0p[k + 3] * wk.w;
            ak1 += x1p[k] * wk.x + x1p[k + 1] * wk.y + x1p[k + 2] * wk.z + x1p[k + 3] * wk.w;
            av0 += x0p[k] * wv.x + x0p[k + 1] * wv.y + x0p[k + 2] * wv.z + x0p[k + 3] * wv.w;
            av1 += x1p[k] * wv.x + x1p[k + 1] * wv.y + x1p[k + 2] * wv.z + x1p[k + 3] * wv.w;
        }
        if (kh) {
            parts[h] = aq0; parts[128 + h] = aq1;
            pk[h] = ak0; pk[128 + h] = ak1;
            pv[h] = av0; pv[128 + h] = av1;
        }
        __syncthreads();
        if (!kh) {
            int s0 = r0 & (Sn - 1), s1_ = (r0 + 1) & (Sn - 1);
            Q[r0 * 128 + h]       = aq0 + parts[h]       + Qb[h];
            Q[(r0 + 1) * 128 + h] = aq1 + parts[128 + h] + Qb[h];
            K[r0 * 128 + h]       = ak0 + pk[h]          + Kb[h] + posK[s0 * 128 + h];
            K[(r0 + 1) * 128 + h] = ak1 + pk[128 + h]    + Kb[h] + posK[s1_ * 128 + h];
            V[r0 * 128 + h]       = av0 + pv[h]          + Vb[h] + posV[s0 * 128 + h];
            V[(r0 + 1) * 128 + h] = av1 + pv[128 + h]    + Vb[h] + posV[s1_ * 128 + h];
        }
    }
}

// ===========================================================================
// Attention v4: block = (b,h, pair j): 8 queries {j*4..+3} U {(127-j)*4..+3}.
// Single pass: each K/V tile staged once for all 8 queries. trow staged in
// LDS. tVw gather replaced by LDS histogram + dense GEMV over 257 t-rows.
// ===========================================================================
__global__ __launch_bounds__(256) void attn_kernel(
    const int* __restrict__ ids, const int* __restrict__ tmat,
    const float* __restrict__ Q, const float* __restrict__ K,
    const float* __restrict__ V,
    const float* __restrict__ tKw, const float* __restrict__ tVw,
    float* __restrict__ O)
{
    __shared__ float Kt[64 * 33];       // K/V tile
    __shared__ float S[8 * 512];        // scores
    __shared__ float QTl[8 * 260];      // Q . timeK[t]
    __shared__ float ql[8 * 33];        // q fragments
    __shared__ float wh[8 * 260];       // histogram weights
    __shared__ int   trowL[8 * 512];    // staged time rows
    __shared__ float invl[8];
    __shared__ int   tlf[8];

    int blk = blockIdx.x, t = threadIdx.x;
    int b8 = blk >> 6, jp = blk & 63;
    int b = b8 >> 2, h = b8 & 3;
    int qlow = jp * 4, qhigh = (127 - jp) * 4;

    if (t < 8) {
        int qg = (t < 4) ? qlow + t : qhigh + t - 4;
        tlf[t] = (ids[b * Sn + qg] == 0) ? 1 : 0;
    }
    {
        int s = t >> 5, d = t & 31;
        int qg = (s < 4) ? qlow + s : qhigh + s - 4;
        ql[s * 33 + d] = Q[(b * Sn + qg) * Hn + h * 32 + d];
    }
    for (int f = t; f < 8 * 260; f += 256) wh[f] = 0.f;
    __syncthreads();

    // fused QT: thread tt computes Q_s . timeK[tt] for the 8 queries
    for (int tt = t; tt < Tt; tt += 256) {
        const float4* tk4 = (const float4*)(tKw + tt * Hn + h * 32);
        float a[8] = {0.f, 0.f, 0.f, 0.f, 0.f, 0.f, 0.f, 0.f};
#pragma unroll
        for (int dv = 0; dv < 8; ++dv) {
            float4 w4 = tk4[dv];
            int d = dv * 4;
#pragma unroll
            for (int s = 0; s < 8; ++s) {
                a[s] += ql[s * 33 + d] * w4.x + ql[s * 33 + d + 1] * w4.y +
                        ql[s * 33 + d + 2] * w4.z + ql[s * 33 + d + 3] * w4.w;
            }
        }
#pragma unroll
        for (int s = 0; s < 8; ++s) QTl[s * 260 + tt] = a[s];
    }

    int tl_any = tlf[0] | tlf[1] | tlf[2] | tlf[3] |
                 tlf[4] | tlf[5] | tlf[6] | tlf[7];
    int ntiles = tl_any ? 8 : ((qhigh + 3) >> 6) + 1;
    int n = ntiles * 64;

    // stage time rows (coalesced, once)
#pragma unroll
    for (int s = 0; s < 8; ++s) {
        int qg = (s < 4) ? qlow + s : qhigh + s - 4;
        const int* tr = tmat + (b * Sn + qg) * Sn;
        for (int j = t; j < n; j += 256) trowL[s * 512 + j] = tr[j];
    }

    int iq = t >> 6, jj = t & 63;
    int sA = iq, sB = iq + 4;
    int iA = qlow + iq, iB = qhigh + iq;
    int tlA = tlf[sA], tlB = tlf[sB];

    // ---- scores: each staged K column feeds both query halves ----
    for (int jt = 0; jt < ntiles; ++jt) {
        int j0 = jt * 64;
        __syncthreads();
        for (int f = t; f < 64 * 8; f += 256) {
            int jl = f >> 3, dv = f & 7;
            float4 w4 = *(const float4*)(K + (b * Sn + j0 + jl) * Hn + h * 32 + dv * 4);
            float* kd = &Kt[jl * 33 + dv * 4];
            kd[0] = w4.x; kd[1] = w4.y; kd[2] = w4.z; kd[3] = w4.w;
        }
        __syncthreads();
        int j = j0 + jj;
        float accA = 0.f, accB = 0.f;
#pragma unroll
        for (int d = 0; d < 32; ++d) {
            float kv = Kt[jj * 33 + d];
            accA += ql[sA * 33 + d] * kv;
            accB += ql[sB * 33 + d] * kv;
        }
        float svA = NEGF, svB = NEGF;
        if (!tlA && j <= iA)
            svA = (accA + QTl[sA * 260 + trowL[sA * 512 + j]]) * INV_SQRT_D;
        if (!tlB && j <= iB)
            svB = (accB + QTl[sB * 260 + trowL[sB * 512 + j]]) * INV_SQRT_D;
        S[sA * 512 + j] = svA;
        S[sB * 512 + j] = svB;
    }

    // ---- per-wave softmax + histogram build (wave iq owns rows sA, sB) ----
#pragma unroll
    for (int ss = 0; ss < 2; ++ss) {
        int s = iq + ss * 4;
        float lm = -INFINITY;
        for (int j = jj; j < n; j += 64) lm = fmaxf(lm, S[s * 512 + j]);
        lm = red64max(lm);
        float ls = 0.f;
        for (int j = jj; j < n; j += 64) {
            float e = expf(S[s * 512 + j] - lm);
            S[s * 512 + j] = e;
            ls += e;
        }
        ls = red64(ls);
        if (jj == 0) invl[s] = 1.f / ls;
        for (int j = jj; j < n; j += 64)
            atomicAdd(&wh[s * 260 + trowL[s * 512 + j]], S[s * 512 + j]);
    }

    // ---- PV (V part): thread = (slot q, dim d) ----
    int q = t >> 5, d = t & 31;
    float accV = 0.f;
    for (int jt = 0; jt < ntiles; ++jt) {
        int j0 = jt * 64;
        __syncthreads();
        for (int f = t; f < 64 * 8; f += 256) {
            int jl = f >> 3, dv = f & 7;
            float4 w4 = *(const float4*)(V + (b * Sn + j0 + jl) * Hn + h * 32 + dv * 4);
            float* kd = &Kt[jl * 33 + dv * 4];
            kd[0] = w4.x; kd[1] = w4.y; kd[2] = w4.z; kd[3] = w4.w;
        }
        __syncthreads();
#pragma unroll 8
        for (int jl = 0; jl < 64; ++jl)
            accV += S[q * 512 + j0 + jl] * Kt[jl * 33 + d];
    }

    // ---- time part: dense GEMV over the 257 t-rows ----
    float accT = 0.f;
    {
        const float* tvb = tVw + h * 32 + d;
        const float* wq = wh + q * 260;
#pragma unroll 8
        for (int tt = 0; tt < Tt; ++tt)
            accT += wq[tt] * tvb[tt * Hn];
    }

    int qg = (q < 4) ? qlow + q : qhigh + q - 4;
    O[(b * Sn + qg) * Hn + h * 32 + d] = (accV + accT) * invl[q];
}

// ===========================================================================
// FFN(nb) -> [attnLN(nb+1)+QKV(nb+1)] or [final LN -> out]. 2 rows/block.
// (unchanged from round 13)
// ===========================================================================
__global__ __launch_bounds__(256) void ffn_qkv_kernel(
    const int* __restrict__ ids, float* __restrict__ Qn,
    const float* __restrict__ O,
    const float* __restrict__ flng, const float* __restrict__ flnb,
    const float* __restrict__ w1W, const float* __restrict__ w1b,
    const float* __restrict__ w2W, const float* __restrict__ w2b,
    const float* __restrict__ alng, const float* __restrict__ alnb,
    const float* __restrict__ QW, const float* __restrict__ Qb,
    const float* __restrict__ KW, const float* __restrict__ Kb,
    const float* __restrict__ VW, const float* __restrict__ Vb,
    const float* __restrict__ posK, const float* __restrict__ posV,
    float* __restrict__ Q, float* __restrict__ K, float* __restrict__ V,
    const float* __restrict__ llng, const float* __restrict__ llnb,
    float* __restrict__ out, int nb, int last)
{
    int r0 = blockIdx.x * 2, t = threadIdx.x;
    __shared__ float ys[256], h1s[256], parts[256], pk[256], pv[256];
    __shared__ float wsum[8];
    ys[t] = Qn[r0 * 128 + t] + O[r0 * 128 + t];
    __syncthreads();
    int w_ = t >> 6, row = w_ >> 1, l = t & 63, ch = ((w_ & 1) << 6) + l;
    float x = ys[row * 128 + ch];
    float s1 = red64(x);
    if (l == 0) wsum[w_] = s1;
    __syncthreads();
    float mean = (wsum[row * 2] + wsum[row * 2 + 1]) * (1.f / 128.f);
    float dlt = x - mean;
    float s2 = red64(dlt * dlt);
    if (l == 0) wsum[4 + w_] = s2;
    __syncthreads();
    float rstd = rsqrtf((wsum[4 + row * 2] + wsum[4 + row * 2 + 1]) * (1.f / 128.f) + EPSF);
    float yv = dlt * rstd * flng[nb * 128 + ch] + flnb[nb * 128 + ch];
    __syncthreads();
    ys[row * 128 + ch] = yv;
    __syncthreads();

    int h = t & 127, kh = t >> 7;
    {
        const float4* w4p = (const float4*)(w1W + nb * 16384 + h * 128 + kh * 64);
        const float* y0 = ys + kh * 64;
        const float* y1 = ys + 128 + kh * 64;
        float a0 = 0.f, a1 = 0.f, b0 = 0.f, b1 = 0.f;
#pragma unroll 16
        for (int k4 = 0; k4 < 16; ++k4) {
            float4 w4 = w4p[k4];
            int k = k4 * 4;
            a0 += y0[k] * w4.x + y0[k + 1] * w4.y;
            a1 += y0[k + 2] * w4.z + y0[k + 3] * w4.w;
            b0 += y1[k] * w4.x + y1[k + 1] * w4.y;
            b1 += y1[k + 2] * w4.z + y1[k + 3] * w4.w;
        }
        float A0 = a0 + a1, A1 = b0 + b1;
        if (kh) { parts[h] = A0; parts[128 + h] = A1; }
        __syncthreads();
        if (!kh) {
            float v0 = A0 + parts[h] + w1b[nb * 128 + h];
            float v1 = A1 + parts[128 + h] + w1b[nb * 128 + h];
            h1s[h] = 0.5f * v0 * (1.f + erff(v0 * 0.70710678118654752f));
            h1s[128 + h] = 0.5f * v1 * (1.f + erff(v1 * 0.70710678118654752f));
        }
    }
    __syncthreads();
    {
        const float4* w4p = (const float4*)(w2W + nb * 16384 + h * 128 + kh * 64);
        const float* y0 = h1s + kh * 64;
        const float* y1 = h1s + 128 + kh * 64;
        float a0 = 0.f, a1 = 0.f, b0 = 0.f, b1 = 0.f;
#pragma unroll 16
        for (int k4 = 0; k4 < 16; ++k4) {
            float4 w4 = w4p[k4];
            int k = k4 * 4;
            a0 += y0[k] * w4.x + y0[k + 1] * w4.y;
            a1 += y0[k + 2] * w4.z + y0[k + 3] * w4.w;
            b0 += y1[k] * w4.x + y1[k + 1] * w4.y;
            b1 += y1[k + 2] * w4.z + y1[k + 3] * w4.w;
        }
        float A0 = a0 + a1, A1 = b0 + b1;
        __syncthreads();
        if (kh) { parts[h] = A0; parts[128 + h] = A1; }
        __syncthreads();
        if (!kh) {
            float z0 = A0 + parts[h] + w2b[nb * 128 + h] + ys[h];
            float z1 = A1 + parts[128 + h] + w2b[nb * 128 + h] + ys[128 + h];
            z0 = (ids[r0] == 0) ? 0.f : z0;
            z1 = (ids[r0 + 1] == 0) ? 0.f : z1;
            h1s[h] = z0; h1s[128 + h] = z1;
        }
    }
    __syncthreads();

    if (last) {
        x = h1s[row * 128 + ch];
        s1 = red64(x);
        if (l == 0) wsum[w_] = s1;
        __syncthreads();
        mean = (wsum[row * 2] + wsum[row * 2 + 1]) * (1.f / 128.f);
        dlt = x - mean;
        s2 = red64(dlt * dlt);
        if (l == 0) wsum[4 + w_] = s2;
        __syncthreads();
        rstd = rsqrtf((wsum[4 + row * 2] + wsum[4 + row * 2 + 1]) * (1.f / 128.f) + EPSF);
        out[(r0 + row) * 128 + ch] = dlt * rstd * llng[ch] + llnb[ch];
        return;
    }

    int nq = nb + 1;
    x = h1s[row * 128 + ch];
    s1 = red64(x);
    if (l == 0) wsum[w_] = s1;
    __syncthreads();
    mean = (wsum[row * 2] + wsum[row * 2 + 1]) * (1.f / 128.f);
    dlt = x - mean;
    s2 = red64(dlt * dlt);
    if (l == 0) wsum[4 + w_] = s2;
    __syncthreads();
    rstd = rsqrtf((wsum[4 + row * 2] + wsum[4 + row * 2 + 1]) * (1.f / 128.f) + EPSF);
    float qn = dlt * rstd * alng[nq * 128 + ch] + alnb[nq * 128 + ch];
    __syncthreads();
    ys[row * 128 + ch] = qn;
    Qn[(r0 + row) * 128 + ch] = qn;
    __syncthreads();

    {
        const float4* qw4 = (const float4*)(QW + nq * 16384 + h * 128 + kh * 64);
        const float4* kw4 = (const float4*)(KW + nq * 16384 + h * 128 + kh * 64);
        const float4* vw4 = (const float4*)(VW + nq * 16384 + h * 128 + kh * 64);
        const float* q0p = ys + kh * 64;
        const float* q1p = ys + 128 + kh * 64;
        const float* x0p = h1s + kh * 64;
        const float* x1p = h1s + 128 + kh * 64;
        float aq0 = 0, aq1 = 0, ak0 = 0, ak1 = 0, av0 = 0, av1 = 0;
#pragma unroll 8
        for (int k4 = 0; k4 < 16; ++k4) {
            float4 wq = qw4[k4], wk = kw4[k4], wv = vw4[k4];
            int k = k4 * 4;
            aq0 += q0p[k] * wq.x + q0p[k + 1] * wq.y + q0p[k + 2] * wq.z + q0p[k + 3] * wq.w;
            aq1 += q1p[k] * wq.x + q1p[k + 1] * wq.y + q1p[k + 2] * wq.z + q1p[k + 3] * wq.w;
            ak0 += x0p[k] * wk.x + x0p[k + 1] * wk.y + x0p[k + 2] * wk.z + x0p[k + 3] * wk.w;
            ak1 += x1p[k] * wk.x + x1p[k + 1] * wk.y + x1p[k + 2] * wk.z + x1p[k + 3] * wk.w;
            av0 += x0p[k] * wv.x + x0p[k + 1] * wv.y + x0p[k + 2] * wv.z + x0p[k + 3] * wv.w;
            av1 += x1p[k] * wv.x + x1p[k + 1] * wv.y + x1p[k + 2] * wv.z + x1p[k + 3] * wv.w;
        }
        if (kh) {
            parts[h] = aq0; parts[128 + h] = aq1;
            pk[h] = ak0; pk[128 + h] = ak1;
            pv[h] = av0; pv[128 + h] = av1;
        }
        __syncthreads();
        if (!kh) {
            int s0 = r0 & (Sn - 1), s1_ = (r0 + 1) & (Sn - 1);
            Q[r0 * 128 + h]       = aq0 + parts[h]       + Qb[nq * 128 + h];
            Q[(r0 + 1) * 128 + h] = aq1 + parts[128 + h] + Qb[nq * 128 + h];
            K[r0 * 128 + h]       = ak0 + pk[h]          + Kb[nq * 128 + h] + posK[s0 * 128 + h];
            K[(r0 + 1) * 128 + h] = ak1 + pk[128 + h]    + Kb[nq * 128 + h] + posK[s1_ * 128 + h];
            V[r0 * 128 + h]       = av0 + pv[h]          + Vb[nq * 128 + h] + posV[s0 * 128 + h];
            V[(r0 + 1) * 128 + h] = av1 + pv[128 + h]    + Vb[nq * 128 + h] + posV[s1_ * 128 + h];
        }
    }
}

// ---------------------------------------------------------------------------
extern "C" void kernel_launch(void* const* d_in, const int* in_sizes, int n_in,
                              void* d_out, int out_size, void* d_ws, size_t ws_size,
                              hipStream_t stream) {
    const int*   ids   = (const int*)  d_in[0];
    const float* meta  = (const float*)d_in[1];
    const int*   cats  = (const int*)  d_in[2];
    const int*   tmat  = (const int*)  d_in[3];
    const float* itemw = (const float*)d_in[4];
    const float* catw  = (const float*)d_in[5];
    const float* numW  = (const float*)d_in[6];
    const float* numb  = (const float*)d_in[7];
    const float* fusW  = (const float*)d_in[8];
    const float* fusb  = (const float*)d_in[9];
    const float* elng  = (const float*)d_in[10];
    const float* elnb  = (const float*)d_in[11];
    const float* posK  = (const float*)d_in[12];
    const float* posV  = (const float*)d_in[13];
    const float* tKw   = (const float*)d_in[14];
    const float* tVw   = (const float*)d_in[15];
    const float* alng  = (const float*)d_in[16];
    const float* alnb  = (const float*)d_in[17];
    const float* QW    = (const float*)d_in[18];
    const float* Qb    = (const float*)d_in[19];
    const float* KW    = (const float*)d_in[20];
    const float* Kb    = (const float*)d_in[21];
    const float* VW    = (const float*)d_in[22];
    const float* Vb    = (const float*)d_in[23];
    const float* flng  = (const float*)d_in[24];
    const float* flnb  = (const float*)d_in[25];
    const float* w1W   = (const float*)d_in[26];
    const float* w1b   = (const float*)d_in[27];
    const float* w2W   = (const float*)d_in[28];
    const float* w2b   = (const float*)d_in[29];
    const float* llng  = (const float*)d_in[30];
    const float* llnb  = (const float*)d_in[31];
    (void)in_sizes; (void)n_in; (void)out_size; (void)ws_size;

    float* ws = (float*)d_ws;
    float* Qn   = ws + OFF_QN;
    float* Q    = ws + OFF_Q;
    float* K    = ws + OFF_K;
    float* V    = ws + OFF_V;
    float* O    = ws + OFF_O;
    float* out  = (float*)d_out;

    embed_qkv_kernel<<<ROWS / 2, 256, 0, stream>>>(
        ids, meta, cats, itemw, catw, numW, numb, fusW, fusb, elng, elnb,
        alng, alnb, QW, Qb, KW, Kb, VW, Vb, posK, posV, Qn, Q, K, V);
    for (int nb = 0; nb < NBn; ++nb) {
        attn_kernel<<<512, 256, 0, stream>>>(ids, tmat, Q, K, V, tKw, tVw, O);
        ffn_qkv_kernel<<<ROWS / 2, 256, 0, stream>>>(
            ids, Qn, O, flng, flnb, w1W, w1b, w2W, w2b,
            alng, alnb, QW, Qb, KW, Kb, VW, Vb, posK, posV,
            Q, K, V, llng, llnb, out, nb, (nb == NBn - 1) ? 1 : 0);
    }
}

// Round 15
// 280.087 us; speedup vs baseline: 1.0941x; 1.0941x over previous
//
#include <hip/hip_runtime.h>
#include <math.h>

// Problem constants
#define Bn 2
#define Sn 512
#define Hn 128
#define NHn 4
#define Dn 32
#define BAGn 5
#define NMETAn 16
#define ROWS 1024
#define NBn 2
#define Tt 257

#define NEGF (-4294967295.0f)
#define INV_SQRT_D 0.17677669529663687f
#define SQRT_H 11.313708498984761f
#define EPS_EMB 1e-5f
#define EPSF 1e-8f

// workspace float offsets
#define OFF_QN    0
#define OFF_Q     131072
#define OFF_K     262144
#define OFF_V     393216
#define OFF_O     524288

static __device__ __forceinline__ float red64(float v) {
#pragma unroll
    for (int m = 1; m < 64; m <<= 1) v += __shfl_xor(v, m, 64);
    return v;
}
static __device__ __forceinline__ float red64max(float v) {
#pragma unroll
    for (int m = 1; m < 64; m <<= 1) v = fmaxf(v, __shfl_xor(v, m, 64));
    return v;
}

// ===========================================================================
// Embed + embLN + keep + attnLN(0) + QKV(0), 2 rows/block (512 blocks).
// (R13 verbatim)
// ===========================================================================
__global__ __launch_bounds__(256) void embed_qkv_kernel(
    const int* __restrict__ ids, const float* __restrict__ meta,
    const int* __restrict__ cats,
    const float* __restrict__ item_w, const float* __restrict__ cat_w,
    const float* __restrict__ numW, const float* __restrict__ numb,
    const float* __restrict__ fusW, const float* __restrict__ fusb,
    const float* __restrict__ elng, const float* __restrict__ elnb,
    const float* __restrict__ alng, const float* __restrict__ alnb,
    const float* __restrict__ QW, const float* __restrict__ Qb,
    const float* __restrict__ KW, const float* __restrict__ Kb,
    const float* __restrict__ VW, const float* __restrict__ Vb,
    const float* __restrict__ posK, const float* __restrict__ posV,
    float* __restrict__ Qn, float* __restrict__ Q,
    float* __restrict__ K, float* __restrict__ V)
{
    int r0 = blockIdx.x * 2, t = threadIdx.x;
    __shared__ float combs[512], xs[256], qs[256], parts[256], pk[256], pv[256];
    __shared__ float wsum[8];
    __shared__ int idl[2];
    if (t < 2) idl[t] = ids[r0 + t];
    __syncthreads();
    { int r = t >> 7, c = t & 127; combs[r * 256 + c] = item_w[idl[r] * Hn + c] * SQRT_H; }
    if (t < 128) {
        int r = t >> 6, c = t & 63;
        float acc = numb[c];
#pragma unroll
        for (int m2 = 0; m2 < NMETAn; ++m2)
            acc += meta[(r0 + r) * NMETAn + m2] * numW[c * NMETAn + m2];
        combs[r * 256 + 128 + c] = acc;
    } else {
        int u = t - 128, r = u >> 6, c = u & 63;
        float ca = 0.f; int cnt = 0;
#pragma unroll
        for (int k2 = 0; k2 < BAGn; ++k2) {
            int cc2 = cats[(r0 + r) * BAGn + k2];
            if (cc2 != 0) { ca += cat_w[cc2 * 64 + c]; cnt++; }
        }
        combs[r * 256 + 192 + c] = ca / (float)(cnt > 0 ? cnt : 1);
    }
    __syncthreads();
    int h = t & 127, kh = t >> 7;
    {
        const float4* w4p = (const float4*)(fusW + h * 256 + kh * 128);
        const float* c0 = combs + kh * 128;
        const float* c1 = combs + 256 + kh * 128;
        float a0 = 0.f, a1 = 0.f, b0 = 0.f, b1 = 0.f;
#pragma unroll 16
        for (int k4 = 0; k4 < 32; ++k4) {
            float4 w4 = w4p[k4];
            int k = k4 * 4;
            a0 += c0[k] * w4.x + c0[k + 1] * w4.y;
            a1 += c0[k + 2] * w4.z + c0[k + 3] * w4.w;
            b0 += c1[k] * w4.x + c1[k + 1] * w4.y;
            b1 += c1[k + 2] * w4.z + c1[k + 3] * w4.w;
        }
        float A0 = a0 + a1, A1 = b0 + b1;
        if (kh) { parts[h] = A0; parts[128 + h] = A1; }
        __syncthreads();
        if (!kh) {
            xs[h] = A0 + parts[h] + fusb[h];
            xs[128 + h] = A1 + parts[128 + h] + fusb[h];
        }
    }
    __syncthreads();
    int w_ = t >> 6, row = w_ >> 1, l = t & 63, ch = ((w_ & 1) << 6) + l;
    float x = xs[row * 128 + ch];
    float s1 = red64(x);
    if (l == 0) wsum[w_] = s1;
    __syncthreads();
    float mean = (wsum[row * 2] + wsum[row * 2 + 1]) * (1.f / 128.f);
    float dlt = x - mean;
    float s2 = red64(dlt * dlt);
    if (l == 0) wsum[4 + w_] = s2;
    __syncthreads();
    float rstd = rsqrtf((wsum[4 + row * 2] + wsum[4 + row * 2 + 1]) * (1.f / 128.f) + EPS_EMB);
    float xv = dlt * rstd * elng[ch] + elnb[ch];
    xv = (idl[row] == 0) ? 0.f : xv;
    __syncthreads();
    xs[row * 128 + ch] = xv;
    __syncthreads();
    s1 = red64(xv);
    if (l == 0) wsum[w_] = s1;
    __syncthreads();
    mean = (wsum[row * 2] + wsum[row * 2 + 1]) * (1.f / 128.f);
    dlt = xv - mean;
    s2 = red64(dlt * dlt);
    if (l == 0) wsum[4 + w_] = s2;
    __syncthreads();
    rstd = rsqrtf((wsum[4 + row * 2] + wsum[4 + row * 2 + 1]) * (1.f / 128.f) + EPSF);
    float qn = dlt * rstd * alng[ch] + alnb[ch];
    qs[row * 128 + ch] = qn;
    Qn[(r0 + row) * 128 + ch] = qn;
    __syncthreads();
    {
        const float4* qw4 = (const float4*)(QW + h * 128 + kh * 64);
        const float4* kw4 = (const float4*)(KW + h * 128 + kh * 64);
        const float4* vw4 = (const float4*)(VW + h * 128 + kh * 64);
        const float* q0p = qs + kh * 64;
        const float* q1p = qs + 128 + kh * 64;
        const float* x0p = xs + kh * 64;
        const float* x1p = xs + 128 + kh * 64;
        float aq0 = 0, aq1 = 0, ak0 = 0, ak1 = 0, av0 = 0, av1 = 0;
#pragma unroll 8
        for (int k4 = 0; k4 < 16; ++k4) {
            float4 wq = qw4[k4], wk = kw4[k4], wv = vw4[k4];
            int k = k4 * 4;
            aq0 += q0p[k] * wq.x + q0p[k + 1] * wq.y + q0p[k + 2] * wq.z + q0p[k + 3] * wq.w;
            aq1 += q1p[k] * wq.x + q1p[k + 1] * wq.y + q1p[k + 2] * wq.z + q1p[k + 3] * wq.w;
            ak0 += x0p[k] * wk.x + x0p[k + 1] * wk.y + x0p[k + 2] * wk.z + x0p[k + 3] * wk.w;
            ak1 += x1p[k] * wk.x + x1p[k + 1] * wk.y + x1p[k + 2] * wk.z + x1p[k + 3] * wk.w;
            av0 += x0p[k] * wv.x + x0p[k + 1] * wv.y + x0p[k + 2] * wv.z + x0p[k + 3] * wv.w;
            av1 += x1p[k] * wv.x + x1p[k + 1] * wv.y + x1p[k + 2] * wv.z + x1p[k + 3] * wv.w;
        }
        if (kh) {
            parts[h] = aq0; parts[128 + h] = aq1;
            pk[h] = ak0; pk[128 + h] = ak1;
            pv[h] = av0; pv[128 + h] = av1;
        }
        __syncthreads();
        if (!kh) {
            int s0 = r0 & (Sn - 1), s1_ = (r0 + 1) & (Sn - 1);
            Q[r0 * 128 + h]       = aq0 + parts[h]       + Qb[h];
            Q[(r0 + 1) * 128 + h] = aq1 + parts[128 + h] + Qb[h];
            K[r0 * 128 + h]       = ak0 + pk[h]          + Kb[h] + posK[s0 * 128 + h];
            K[(r0 + 1) * 128 + h] = ak1 + pk[128 + h]    + Kb[h] + posK[s1_ * 128 + h];
            V[r0 * 128 + h]       = av0 + pv[h]          + Vb[h] + posV[s0 * 128 + h];
            V[(r0 + 1) * 128 + h] = av1 + pv[128 + h]    + Vb[h] + posV[s1_ * 128 + h];
        }
    }
}

// ===========================================================================
// Attention (R13 structure + q-row hoisted into registers in score pass).
// ===========================================================================
static __device__ __forceinline__ void attn_phase(
    int b, int h, int i0, int t,
    const int* __restrict__ ids, const int* __restrict__ tmat,
    const float* __restrict__ Q, const float* __restrict__ K,
    const float* __restrict__ V,
    const float* __restrict__ tKw, const float* __restrict__ tVw,
    float* __restrict__ O,
    float* Kt, float* S, float* QTl, float* ql, float* aparts, float* invl,
    int* tlf)
{
    __syncthreads();
    if (t < 4) tlf[t] = (ids[b * Sn + i0 + t] == 0) ? 1 : 0;
    if (t < 128) {
        int q_ = t >> 5, d = t & 31;
        ql[q_ * 33 + d] = Q[(b * Sn + i0 + q_) * Hn + h * 32 + d];
    }
    __syncthreads();

    for (int tt = t; tt < Tt; tt += 256) {
        const float4* tk4 = (const float4*)(tKw + tt * Hn + h * 32);
        float a0 = 0.f, a1 = 0.f, a2 = 0.f, a3 = 0.f;
#pragma unroll
        for (int dv = 0; dv < 8; ++dv) {
            float4 w4 = tk4[dv];
            int d = dv * 4;
            a0 += ql[d] * w4.x + ql[d + 1] * w4.y + ql[d + 2] * w4.z + ql[d + 3] * w4.w;
            a1 += ql[33 + d] * w4.x + ql[34 + d] * w4.y + ql[35 + d] * w4.z + ql[36 + d] * w4.w;
            a2 += ql[66 + d] * w4.x + ql[67 + d] * w4.y + ql[68 + d] * w4.z + ql[69 + d] * w4.w;
            a3 += ql[99 + d] * w4.x + ql[100 + d] * w4.y + ql[101 + d] * w4.z + ql[102 + d] * w4.w;
        }
        QTl[tt] = a0; QTl[260 + tt] = a1; QTl[520 + tt] = a2; QTl[780 + tt] = a3;
    }

    int tl_any = tlf[0] | tlf[1] | tlf[2] | tlf[3];
    int ntiles = tl_any ? 8 : ((i0 + 3) >> 6) + 1;
    int n = ntiles * 64;

    int iq = t >> 6, jj = t & 63;
    int i_g = i0 + iq;
    int my_tl = tlf[iq];
    const int* trow = tmat + (b * Sn + i_g) * Sn;

    // hoist this wave's q row into registers (invariant across jt tiles;
    // the barrier inside the loop blocks the compiler from doing this).
    float qreg[32];
#pragma unroll
    for (int d = 0; d < 32; ++d) qreg[d] = ql[iq * 33 + d];

    for (int jt = 0; jt < ntiles; ++jt) {
        int j0 = jt * 64;
        __syncthreads();
        for (int f = t; f < 64 * 8; f += 256) {
            int jl = f >> 3, dv = f & 7;
            float4 w4 = *(const float4*)(K + (b * Sn + j0 + jl) * Hn + h * 32 + dv * 4);
            float* kd = &Kt[jl * 33 + dv * 4];
            kd[0] = w4.x; kd[1] = w4.y; kd[2] = w4.z; kd[3] = w4.w;
        }
        __syncthreads();
        int j = j0 + jj;
        float sv = NEGF;
        if (!my_tl && j <= i_g) {
            float acc = 0.f;
#pragma unroll
            for (int d = 0; d < 32; ++d)
                acc += qreg[d] * Kt[jj * 33 + d];
            sv = (acc + QTl[iq * 260 + trow[j]]) * INV_SQRT_D;
        }
        S[iq * 512 + j] = sv;
    }

    float lm = -INFINITY;
    for (int j = jj; j < n; j += 64) lm = fmaxf(lm, S[iq * 512 + j]);
    lm = red64max(lm);
    float ls = 0.f;
    for (int j = jj; j < n; j += 64) {
        float e = expf(S[iq * 512 + j] - lm);
        S[iq * 512 + j] = e;
        ls += e;
    }
    ls = red64(ls);
    if (jj == 0) invl[iq] = 1.f / ls;

    int jq = (t >> 5) & 1, d = t & 31;
    float acc = 0.f;
    for (int jt = 0; jt < ntiles; ++jt) {
        int j0 = jt * 64;
        __syncthreads();
        for (int f = t; f < 64 * 8; f += 256) {
            int jl = f >> 3, dv = f & 7;
            float4 w4 = *(const float4*)(V + (b * Sn + j0 + jl) * Hn + h * 32 + dv * 4);
            float* kd = &Kt[jl * 33 + dv * 4];
            kd[0] = w4.x; kd[1] = w4.y; kd[2] = w4.z; kd[3] = w4.w;
        }
        __syncthreads();
        if (my_tl || j0 <= i_g) {
#pragma unroll 8
            for (int jl = jq * 32; jl < jq * 32 + 32; ++jl) {
                int j = j0 + jl;
                float p = S[iq * 512 + j];
                int tv = trow[j];
                acc += p * (Kt[jl * 33 + d] + tVw[tv * Hn + h * 32 + d]);
            }
        }
    }
    aparts[t] = acc;
    __syncthreads();
    if (t < 128) {
        int iq2 = t >> 5, d2 = t & 31;
        float a = aparts[iq2 * 64 + d2] + aparts[iq2 * 64 + 32 + d2];
        O[(b * Sn + i0 + iq2) * Hn + h * 32 + d2] = a * invl[iq2];
    }
}

__global__ __launch_bounds__(256) void attn_kernel(
    const int* ids, const int* tmat,
    const float* Q, const float* K, const float* V,
    const float* tKw, const float* tVw, float* O)
{
    __shared__ float Kt[64 * 33];
    __shared__ float S[4 * 512];
    __shared__ float QTl[4 * 260];
    __shared__ float ql[4 * 33];
    __shared__ float aparts[256];
    __shared__ float invl[4];
    __shared__ int tlf[4];
    int blk = blockIdx.x, t = threadIdx.x;
    int b8 = blk >> 6, j = blk & 63;
    int b = b8 >> 2, h = b8 & 3;
    attn_phase(b, h, j * 4, t, ids, tmat, Q, K, V, tKw, tVw, O,
               Kt, S, QTl, ql, aparts, invl, tlf);
    attn_phase(b, h, (127 - j) * 4, t, ids, tmat, Q, K, V, tKw, tVw, O,
               Kt, S, QTl, ql, aparts, invl, tlf);
}

// ===========================================================================
// FFN(nb) -> [attnLN(nb+1)+QKV(nb+1)] or [final LN -> out]. 2 rows/block.
// (R13 verbatim)
// ===========================================================================
__global__ __launch_bounds__(256) void ffn_qkv_kernel(
    const int* __restrict__ ids, float* __restrict__ Qn,
    const float* __restrict__ O,
    const float* __restrict__ flng, const float* __restrict__ flnb,
    const float* __restrict__ w1W, const float* __restrict__ w1b,
    const float* __restrict__ w2W, const float* __restrict__ w2b,
    const float* __restrict__ alng, const float* __restrict__ alnb,
    const float* __restrict__ QW, const float* __restrict__ Qb,
    const float* __restrict__ KW, const float* __restrict__ Kb,
    const float* __restrict__ VW, const float* __restrict__ Vb,
    const float* __restrict__ posK, const float* __restrict__ posV,
    float* __restrict__ Q, float* __restrict__ K, float* __restrict__ V,
    const float* __restrict__ llng, const float* __restrict__ llnb,
    float* __restrict__ out, int nb, int last)
{
    int r0 = blockIdx.x * 2, t = threadIdx.x;
    __shared__ float ys[256], h1s[256], parts[256], pk[256], pv[256];
    __shared__ float wsum[8];
    ys[t] = Qn[r0 * 128 + t] + O[r0 * 128 + t];
    __syncthreads();
    int w_ = t >> 6, row = w_ >> 1, l = t & 63, ch = ((w_ & 1) << 6) + l;
    float x = ys[row * 128 + ch];
    float s1 = red64(x);
    if (l == 0) wsum[w_] = s1;
    __syncthreads();
    float mean = (wsum[row * 2] + wsum[row * 2 + 1]) * (1.f / 128.f);
    float dlt = x - mean;
    float s2 = red64(dlt * dlt);
    if (l == 0) wsum[4 + w_] = s2;
    __syncthreads();
    float rstd = rsqrtf((wsum[4 + row * 2] + wsum[4 + row * 2 + 1]) * (1.f / 128.f) + EPSF);
    float yv = dlt * rstd * flng[nb * 128 + ch] + flnb[nb * 128 + ch];
    __syncthreads();
    ys[row * 128 + ch] = yv;
    __syncthreads();

    int h = t & 127, kh = t >> 7;
    {
        const float4* w4p = (const float4*)(w1W + nb * 16384 + h * 128 + kh * 64);
        const float* y0 = ys + kh * 64;
        const float* y1 = ys + 128 + kh * 64;
        float a0 = 0.f, a1 = 0.f, b0 = 0.f, b1 = 0.f;
#pragma unroll 16
        for (int k4 = 0; k4 < 16; ++k4) {
            float4 w4 = w4p[k4];
            int k = k4 * 4;
            a0 += y0[k] * w4.x + y0[k + 1] * w4.y;
            a1 += y0[k + 2] * w4.z + y0[k + 3] * w4.w;
            b0 += y1[k] * w4.x + y1[k + 1] * w4.y;
            b1 += y1[k + 2] * w4.z + y1[k + 3] * w4.w;
        }
        float A0 = a0 + a1, A1 = b0 + b1;
        if (kh) { parts[h] = A0; parts[128 + h] = A1; }
        __syncthreads();
        if (!kh) {
            float v0 = A0 + parts[h] + w1b[nb * 128 + h];
            float v1 = A1 + parts[128 + h] + w1b[nb * 128 + h];
            h1s[h] = 0.5f * v0 * (1.f + erff(v0 * 0.70710678118654752f));
            h1s[128 + h] = 0.5f * v1 * (1.f + erff(v1 * 0.70710678118654752f));
        }
    }
    __syncthreads();
    {
        const float4* w4p = (const float4*)(w2W + nb * 16384 + h * 128 + kh * 64);
        const float* y0 = h1s + kh * 64;
        const float* y1 = h1s + 128 + kh * 64;
        float a0 = 0.f, a1 = 0.f, b0 = 0.f, b1 = 0.f;
#pragma unroll 16
        for (int k4 = 0; k4 < 16; ++k4) {
            float4 w4 = w4p[k4];
            int k = k4 * 4;
            a0 += y0[k] * w4.x + y0[k + 1] * w4.y;
            a1 += y0[k + 2] * w4.z + y0[k + 3] * w4.w;
            b0 += y1[k] * w4.x + y1[k + 1] * w4.y;
            b1 += y1[k + 2] * w4.z + y1[k + 3] * w4.w;
        }
        float A0 = a0 + a1, A1 = b0 + b1;
        __syncthreads();
        if (kh) { parts[h] = A0; parts[128 + h] = A1; }
        __syncthreads();
        if (!kh) {
            float z0 = A0 + parts[h] + w2b[nb * 128 + h] + ys[h];
            float z1 = A1 + parts[128 + h] + w2b[nb * 128 + h] + ys[128 + h];
            z0 = (ids[r0] == 0) ? 0.f : z0;
            z1 = (ids[r0 + 1] == 0) ? 0.f : z1;
            h1s[h] = z0; h1s[128 + h] = z1;
        }
    }
    __syncthreads();

    if (last) {
        x = h1s[row * 128 + ch];
        s1 = red64(x);
        if (l == 0) wsum[w_] = s1;
        __syncthreads();
        mean = (wsum[row * 2] + wsum[row * 2 + 1]) * (1.f / 128.f);
        dlt = x - mean;
        s2 = red64(dlt * dlt);
        if (l == 0) wsum[4 + w_] = s2;
        __syncthreads();
        rstd = rsqrtf((wsum[4 + row * 2] + wsum[4 + row * 2 + 1]) * (1.f / 128.f) + EPSF);
        out[(r0 + row) * 128 + ch] = dlt * rstd * llng[ch] + llnb[ch];
        return;
    }

    int nq = nb + 1;
    x = h1s[row * 128 + ch];
    s1 = red64(x);
    if (l == 0) wsum[w_] = s1;
    __syncthreads();
    mean = (wsum[row * 2] + wsum[row * 2 + 1]) * (1.f / 128.f);
    dlt = x - mean;
    s2 = red64(dlt * dlt);
    if (l == 0) wsum[4 + w_] = s2;
    __syncthreads();
    rstd = rsqrtf((wsum[4 + row * 2] + wsum[4 + row * 2 + 1]) * (1.f / 128.f) + EPSF);
    float qn = dlt * rstd * alng[nq * 128 + ch] + alnb[nq * 128 + ch];
    __syncthreads();
    ys[row * 128 + ch] = qn;
    Qn[(r0 + row) * 128 + ch] = qn;
    __syncthreads();

    {
        const float4* qw4 = (const float4*)(QW + nq * 16384 + h * 128 + kh * 64);
        const float4* kw4 = (const float4*)(KW + nq * 16384 + h * 128 + kh * 64);
        const float4* vw4 = (const float4*)(VW + nq * 16384 + h * 128 + kh * 64);
        const float* q0p = ys + kh * 64;
        const float* q1p = ys + 128 + kh * 64;
        const float* x0p = h1s + kh * 64;
        const float* x1p = h1s + 128 + kh * 64;
        float aq0 = 0, aq1 = 0, ak0 = 0, ak1 = 0, av0 = 0, av1 = 0;
#pragma unroll 8
        for (int k4 = 0; k4 < 16; ++k4) {
            float4 wq = qw4[k4], wk = kw4[k4], wv = vw4[k4];
            int k = k4 * 4;
            aq0 += q0p[k] * wq.x + q0p[k + 1] * wq.y + q0p[k + 2] * wq.z + q0p[k + 3] * wq.w;
            aq1 += q1p[k] * wq.x + q1p[k + 1] * wq.y + q1p[k + 2] * wq.z + q1p[k + 3] * wq.w;
            ak0 += x0p[k] * wk.x + x0p[k + 1] * wk.y + x0p[k + 2] * wk.z + x0p[k + 3] * wk.w;
            ak1 += x1p[k] * wk.x + x1p[k + 1] * wk.y + x1p[k + 2] * wk.z + x1p[k + 3] * wk.w;
            av0 += x0p[k] * wv.x + x0p[k + 1] * wv.y + x0p[k + 2] * wv.z + x0p[k + 3] * wv.w;
            av1 += x1p[k] * wv.x + x1p[k + 1] * wv.y + x1p[k + 2] * wv.z + x1p[k + 3] * wv.w;
        }
        if (kh) {
            parts[h] = aq0; parts[128 + h] = aq1;
            pk[h] = ak0; pk[128 + h] = ak1;
            pv[h] = av0; pv[128 + h] = av1;
        }
        __syncthreads();
        if (!kh) {
            int s0 = r0 & (Sn - 1), s1_ = (r0 + 1) & (Sn - 1);
            Q[r0 * 128 + h]       = aq0 + parts[h]       + Qb[nq * 128 + h];
            Q[(r0 + 1) * 128 + h] = aq1 + parts[128 + h] + Qb[nq * 128 + h];
            K[r0 * 128 + h]       = ak0 + pk[h]          + Kb[nq * 128 + h] + posK[s0 * 128 + h];
            K[(r0 + 1) * 128 + h] = ak1 + pk[128 + h]    + Kb[nq * 128 + h] + posK[s1_ * 128 + h];
            V[r0 * 128 + h]       = av0 + pv[h]          + Vb[nq * 128 + h] + posV[s0 * 128 + h];
            V[(r0 + 1) * 128 + h] = av1 + pv[128 + h]    + Vb[nq * 128 + h] + posV[s1_ * 128 + h];
        }
    }
}

// ---------------------------------------------------------------------------
extern "C" void kernel_launch(void* const* d_in, const int* in_sizes, int n_in,
                              void* d_out, int out_size, void* d_ws, size_t ws_size,
                              hipStream_t stream) {
    const int*   ids   = (const int*)  d_in[0];
    const float* meta  = (const float*)d_in[1];
    const int*   cats  = (const int*)  d_in[2];
    const int*   tmat  = (const int*)  d_in[3];
    const float* itemw = (const float*)d_in[4];
    const float* catw  = (const float*)d_in[5];
    const float* numW  = (const float*)d_in[6];
    const float* numb  = (const float*)d_in[7];
    const float* fusW  = (const float*)d_in[8];
    const float* fusb  = (const float*)d_in[9];
    const float* elng  = (const float*)d_in[10];
    const float* elnb  = (const float*)d_in[11];
    const float* posK  = (const float*)d_in[12];
    const float* posV  = (const float*)d_in[13];
    const float* tKw   = (const float*)d_in[14];
    const float* tVw   = (const float*)d_in[15];
    const float* alng  = (const float*)d_in[16];
    const float* alnb  = (const float*)d_in[17];
    const float* QW    = (const float*)d_in[18];
    const float* Qb    = (const float*)d_in[19];
    const float* KW    = (const float*)d_in[20];
    const float* Kb    = (const float*)d_in[21];
    const float* VW    = (const float*)d_in[22];
    const float* Vb    = (const float*)d_in[23];
    const float* flng  = (const float*)d_in[24];
    const float* flnb  = (const float*)d_in[25];
    const float* w1W   = (const float*)d_in[26];
    const float* w1b   = (const float*)d_in[27];
    const float* w2W   = (const float*)d_in[28];
    const float* w2b   = (const float*)d_in[29];
    const float* llng  = (const float*)d_in[30];
    const float* llnb  = (const float*)d_in[31];
    (void)in_sizes; (void)n_in; (void)out_size; (void)ws_size;

    float* ws = (float*)d_ws;
    float* Qn   = ws + OFF_QN;
    float* Q    = ws + OFF_Q;
    float* K    = ws + OFF_K;
    float* V    = ws + OFF_V;
    float* O    = ws + OFF_O;
    float* out  = (float*)d_out;

    embed_qkv_kernel<<<ROWS / 2, 256, 0, stream>>>(
        ids, meta, cats, itemw, catw, numW, numb, fusW, fusb, elng, elnb,
        alng, alnb, QW, Qb, KW, Kb, VW, Vb, posK, posV, Qn, Q, K, V);
    for (int nb = 0; nb < NBn; ++nb) {
        attn_kernel<<<512, 256, 0, stream>>>(ids, tmat, Q, K, V, tKw, tVw, O);
        ffn_qkv_kernel<<<ROWS / 2, 256, 0, stream>>>(
            ids, Qn, O, flng, flnb, w1W, w1b, w2W, w2b,
            alng, alnb, QW, Qb, KW, Kb, VW, Vb, posK, posV,
            Q, K, V, llng, llnb, out, nb, (nb == NBn - 1) ? 1 : 0);
    }
}

// Round 16
// 271.951 us; speedup vs baseline: 1.1269x; 1.0299x over previous
//
#include <hip/hip_runtime.h>
#include <math.h>

// Problem constants
#define Bn 2
#define Sn 512
#define Hn 128
#define NHn 4
#define Dn 32
#define BAGn 5
#define NMETAn 16
#define ROWS 1024
#define NBn 2
#define Tt 257

#define NEGF (-4294967295.0f)
#define INV_SQRT_D 0.17677669529663687f
#define SQRT_H 11.313708498984761f
#define EPS_EMB 1e-5f
#define EPSF 1e-8f

// workspace float offsets
#define OFF_QN    0
#define OFF_Q     131072
#define OFF_K     262144
#define OFF_V     393216
#define OFF_O     524288

static __device__ __forceinline__ float red64(float v) {
#pragma unroll
    for (int m = 1; m < 64; m <<= 1) v += __shfl_xor(v, m, 64);
    return v;
}
static __device__ __forceinline__ float red64max(float v) {
#pragma unroll
    for (int m = 1; m < 64; m <<= 1) v = fmaxf(v, __shfl_xor(v, m, 64));
    return v;
}

// ===========================================================================
// Embed + embLN + keep + attnLN(0) + QKV(0), 2 rows/block (512 blocks).
// (R13 verbatim)
// ===========================================================================
__global__ __launch_bounds__(256) void embed_qkv_kernel(
    const int* __restrict__ ids, const float* __restrict__ meta,
    const int* __restrict__ cats,
    const float* __restrict__ item_w, const float* __restrict__ cat_w,
    const float* __restrict__ numW, const float* __restrict__ numb,
    const float* __restrict__ fusW, const float* __restrict__ fusb,
    const float* __restrict__ elng, const float* __restrict__ elnb,
    const float* __restrict__ alng, const float* __restrict__ alnb,
    const float* __restrict__ QW, const float* __restrict__ Qb,
    const float* __restrict__ KW, const float* __restrict__ Kb,
    const float* __restrict__ VW, const float* __restrict__ Vb,
    const float* __restrict__ posK, const float* __restrict__ posV,
    float* __restrict__ Qn, float* __restrict__ Q,
    float* __restrict__ K, float* __restrict__ V)
{
    int r0 = blockIdx.x * 2, t = threadIdx.x;
    __shared__ float combs[512], xs[256], qs[256], parts[256], pk[256], pv[256];
    __shared__ float wsum[8];
    __shared__ int idl[2];
    if (t < 2) idl[t] = ids[r0 + t];
    __syncthreads();
    { int r = t >> 7, c = t & 127; combs[r * 256 + c] = item_w[idl[r] * Hn + c] * SQRT_H; }
    if (t < 128) {
        int r = t >> 6, c = t & 63;
        float acc = numb[c];
#pragma unroll
        for (int m2 = 0; m2 < NMETAn; ++m2)
            acc += meta[(r0 + r) * NMETAn + m2] * numW[c * NMETAn + m2];
        combs[r * 256 + 128 + c] = acc;
    } else {
        int u = t - 128, r = u >> 6, c = u & 63;
        float ca = 0.f; int cnt = 0;
#pragma unroll
        for (int k2 = 0; k2 < BAGn; ++k2) {
            int cc2 = cats[(r0 + r) * BAGn + k2];
            if (cc2 != 0) { ca += cat_w[cc2 * 64 + c]; cnt++; }
        }
        combs[r * 256 + 192 + c] = ca / (float)(cnt > 0 ? cnt : 1);
    }
    __syncthreads();
    int h = t & 127, kh = t >> 7;
    {
        const float4* w4p = (const float4*)(fusW + h * 256 + kh * 128);
        const float* c0 = combs + kh * 128;
        const float* c1 = combs + 256 + kh * 128;
        float a0 = 0.f, a1 = 0.f, b0 = 0.f, b1 = 0.f;
#pragma unroll 16
        for (int k4 = 0; k4 < 32; ++k4) {
            float4 w4 = w4p[k4];
            int k = k4 * 4;
            a0 += c0[k] * w4.x + c0[k + 1] * w4.y;
            a1 += c0[k + 2] * w4.z + c0[k + 3] * w4.w;
            b0 += c1[k] * w4.x + c1[k + 1] * w4.y;
            b1 += c1[k + 2] * w4.z + c1[k + 3] * w4.w;
        }
        float A0 = a0 + a1, A1 = b0 + b1;
        if (kh) { parts[h] = A0; parts[128 + h] = A1; }
        __syncthreads();
        if (!kh) {
            xs[h] = A0 + parts[h] + fusb[h];
            xs[128 + h] = A1 + parts[128 + h] + fusb[h];
        }
    }
    __syncthreads();
    int w_ = t >> 6, row = w_ >> 1, l = t & 63, ch = ((w_ & 1) << 6) + l;
    float x = xs[row * 128 + ch];
    float s1 = red64(x);
    if (l == 0) wsum[w_] = s1;
    __syncthreads();
    float mean = (wsum[row * 2] + wsum[row * 2 + 1]) * (1.f / 128.f);
    float dlt = x - mean;
    float s2 = red64(dlt * dlt);
    if (l == 0) wsum[4 + w_] = s2;
    __syncthreads();
    float rstd = rsqrtf((wsum[4 + row * 2] + wsum[4 + row * 2 + 1]) * (1.f / 128.f) + EPS_EMB);
    float xv = dlt * rstd * elng[ch] + elnb[ch];
    xv = (idl[row] == 0) ? 0.f : xv;
    __syncthreads();
    xs[row * 128 + ch] = xv;
    __syncthreads();
    s1 = red64(xv);
    if (l == 0) wsum[w_] = s1;
    __syncthreads();
    mean = (wsum[row * 2] + wsum[row * 2 + 1]) * (1.f / 128.f);
    dlt = xv - mean;
    s2 = red64(dlt * dlt);
    if (l == 0) wsum[4 + w_] = s2;
    __syncthreads();
    rstd = rsqrtf((wsum[4 + row * 2] + wsum[4 + row * 2 + 1]) * (1.f / 128.f) + EPSF);
    float qn = dlt * rstd * alng[ch] + alnb[ch];
    qs[row * 128 + ch] = qn;
    Qn[(r0 + row) * 128 + ch] = qn;
    __syncthreads();
    {
        const float4* qw4 = (const float4*)(QW + h * 128 + kh * 64);
        const float4* kw4 = (const float4*)(KW + h * 128 + kh * 64);
        const float4* vw4 = (const float4*)(VW + h * 128 + kh * 64);
        const float* q0p = qs + kh * 64;
        const float* q1p = qs + 128 + kh * 64;
        const float* x0p = xs + kh * 64;
        const float* x1p = xs + 128 + kh * 64;
        float aq0 = 0, aq1 = 0, ak0 = 0, ak1 = 0, av0 = 0, av1 = 0;
#pragma unroll 8
        for (int k4 = 0; k4 < 16; ++k4) {
            float4 wq = qw4[k4], wk = kw4[k4], wv = vw4[k4];
            int k = k4 * 4;
            aq0 += q0p[k] * wq.x + q0p[k + 1] * wq.y + q0p[k + 2] * wq.z + q0p[k + 3] * wq.w;
            aq1 += q1p[k] * wq.x + q1p[k + 1] * wq.y + q1p[k + 2] * wq.z + q1p[k + 3] * wq.w;
            ak0 += x0p[k] * wk.x + x0p[k + 1] * wk.y + x0p[k + 2] * wk.z + x0p[k + 3] * wk.w;
            ak1 += x1p[k] * wk.x + x1p[k + 1] * wk.y + x1p[k + 2] * wk.z + x1p[k + 3] * wk.w;
            av0 += x0p[k] * wv.x + x0p[k + 1] * wv.y + x0p[k + 2] * wv.z + x0p[k + 3] * wv.w;
            av1 += x1p[k] * wv.x + x1p[k + 1] * wv.y + x1p[k + 2] * wv.z + x1p[k + 3] * wv.w;
        }
        if (kh) {
            parts[h] = aq0; parts[128 + h] = aq1;
            pk[h] = ak0; pk[128 + h] = ak1;
            pv[h] = av0; pv[128 + h] = av1;
        }
        __syncthreads();
        if (!kh) {
            int s0 = r0 & (Sn - 1), s1_ = (r0 + 1) & (Sn - 1);
            Q[r0 * 128 + h]       = aq0 + parts[h]       + Qb[h];
            Q[(r0 + 1) * 128 + h] = aq1 + parts[128 + h] + Qb[h];
            K[r0 * 128 + h]       = ak0 + pk[h]          + Kb[h] + posK[s0 * 128 + h];
            K[(r0 + 1) * 128 + h] = ak1 + pk[128 + h]    + Kb[h] + posK[s1_ * 128 + h];
            V[r0 * 128 + h]       = av0 + pv[h]          + Vb[h] + posV[s0 * 128 + h];
            V[(r0 + 1) * 128 + h] = av1 + pv[128 + h]    + Vb[h] + posV[s1_ * 128 + h];
        }
    }
}

// ===========================================================================
// Attention v5: single-pass flash-style online softmax.
// block = (b,h, balanced pair {j, 127-j}); each phase: 4 queries, row == wave.
// Per tile: stage K+V together, scores -> online rescale (m,l,acc in regs,
// alpha wave-uniform), P+trow via small LDS tile, PV immediately.
// ===========================================================================
static __device__ __forceinline__ void attn_phase(
    int b, int h, int i0, int t,
    const int* __restrict__ ids, const int* __restrict__ tmat,
    const float* __restrict__ Q, const float* __restrict__ K,
    const float* __restrict__ V,
    const float* __restrict__ tKw, const float* __restrict__ tVw,
    float* __restrict__ O,
    float* Kt, float* Vt, float* Stile, int* trowT,
    float* QTl, float* ql, int* tlf)
{
    __syncthreads();
    if (t < 4) tlf[t] = (ids[b * Sn + i0 + t] == 0) ? 1 : 0;
    if (t < 128) {
        int q_ = t >> 5, d = t & 31;
        ql[q_ * 33 + d] = Q[(b * Sn + i0 + q_) * Hn + h * 32 + d];
    }
    __syncthreads();

    // fused QT: thread tt computes Q_i . timeK[tt] for the 4 queries
    for (int tt = t; tt < Tt; tt += 256) {
        const float4* tk4 = (const float4*)(tKw + tt * Hn + h * 32);
        float a0 = 0.f, a1 = 0.f, a2 = 0.f, a3 = 0.f;
#pragma unroll
        for (int dv = 0; dv < 8; ++dv) {
            float4 w4 = tk4[dv];
            int d = dv * 4;
            a0 += ql[d] * w4.x + ql[d + 1] * w4.y + ql[d + 2] * w4.z + ql[d + 3] * w4.w;
            a1 += ql[33 + d] * w4.x + ql[34 + d] * w4.y + ql[35 + d] * w4.z + ql[36 + d] * w4.w;
            a2 += ql[66 + d] * w4.x + ql[67 + d] * w4.y + ql[68 + d] * w4.z + ql[69 + d] * w4.w;
            a3 += ql[99 + d] * w4.x + ql[100 + d] * w4.y + ql[101 + d] * w4.z + ql[102 + d] * w4.w;
        }
        QTl[tt] = a0; QTl[260 + tt] = a1; QTl[520 + tt] = a2; QTl[780 + tt] = a3;
    }

    int tl_any = tlf[0] | tlf[1] | tlf[2] | tlf[3];
    int ntiles = tl_any ? 8 : ((i0 + 3) >> 6) + 1;

    int iq = t >> 6, jj = t & 63;
    int i_g = i0 + iq;
    int my_tl = tlf[iq];
    const int* trow = tmat + (b * Sn + i_g) * Sn;

    float qreg[32];
#pragma unroll
    for (int d = 0; d < 32; ++d) qreg[d] = ql[iq * 33 + d];

    int jq = jj >> 5, d = jj & 31;
    float m = -INFINITY, lsum = 0.f, acc = 0.f;

    for (int jt = 0; jt < ntiles; ++jt) {
        int j0 = jt * 64;
        __syncthreads();           // prior PV done before re-staging
        for (int f = t; f < 64 * 8; f += 256) {
            int jl = f >> 3, dv = f & 7;
            const float* src = K + (b * Sn + j0 + jl) * Hn + h * 32 + dv * 4;
            float4 w4 = *(const float4*)src;
            float* kd = &Kt[jl * 33 + dv * 4];
            kd[0] = w4.x; kd[1] = w4.y; kd[2] = w4.z; kd[3] = w4.w;
            float4 v4 = *(const float4*)(V + (b * Sn + j0 + jl) * Hn + h * 32 + dv * 4);
            float* vd = &Vt[jl * 33 + dv * 4];
            vd[0] = v4.x; vd[1] = v4.y; vd[2] = v4.z; vd[3] = v4.w;
        }
        __syncthreads();

        int active = my_tl || (j0 <= i_g);   // wave-uniform
        if (active) {
            int j = j0 + jj;
            float sv = NEGF;
            int tv = trow[j];
            if (!my_tl && j <= i_g) {
                float a = 0.f;
#pragma unroll
                for (int dd = 0; dd < 32; ++dd)
                    a += qreg[dd] * Kt[jj * 33 + dd];
                sv = (a + QTl[iq * 260 + tv]) * INV_SQRT_D;
            }
            float mt = red64max(sv);
            float mnew = fmaxf(m, mt);
            float alpha = expf(m - mnew);    // m=-inf first tile -> 0
            float p = expf(sv - mnew);
            lsum = lsum * alpha + red64(p);
            m = mnew;
            acc *= alpha;
            Stile[iq * 64 + jj] = p;
            trowT[iq * 64 + jj] = tv;
        }
        __syncthreads();           // Stile/Vt visible (also keeps waves aligned)
        if (active) {
            int base = jq * 32;
#pragma unroll 8
            for (int jl = base; jl < base + 32; ++jl) {
                float pp = Stile[iq * 64 + jl];
                int tv2 = trowT[iq * 64 + jl];
                acc += pp * (Vt[jl * 33 + d] + tVw[tv2 * Hn + h * 32 + d]);
            }
        }
    }

    // finalize: sum the two jq halves, divide by l
    float a2 = acc + __shfl_xor(acc, 32, 64);
    if (jj < 32)
        O[(b * Sn + i_g) * Hn + h * 32 + d] = a2 / lsum;
}

__global__ __launch_bounds__(256) void attn_kernel(
    const int* ids, const int* tmat,
    const float* Q, const float* K, const float* V,
    const float* tKw, const float* tVw, float* O)
{
    __shared__ float Kt[64 * 33];
    __shared__ float Vt[64 * 33];
    __shared__ float Stile[4 * 64];
    __shared__ int   trowT[4 * 64];
    __shared__ float QTl[4 * 260];
    __shared__ float ql[4 * 33];
    __shared__ int tlf[4];
    int blk = blockIdx.x, t = threadIdx.x;
    int b8 = blk >> 6, j = blk & 63;
    int b = b8 >> 2, h = b8 & 3;
    attn_phase(b, h, j * 4, t, ids, tmat, Q, K, V, tKw, tVw, O,
               Kt, Vt, Stile, trowT, QTl, ql, tlf);
    attn_phase(b, h, (127 - j) * 4, t, ids, tmat, Q, K, V, tKw, tVw, O,
               Kt, Vt, Stile, trowT, QTl, ql, tlf);
}

// ===========================================================================
// FFN(nb) -> [attnLN(nb+1)+QKV(nb+1)] or [final LN -> out]. 2 rows/block.
// (R13 verbatim)
// ===========================================================================
__global__ __launch_bounds__(256) void ffn_qkv_kernel(
    const int* __restrict__ ids, float* __restrict__ Qn,
    const float* __restrict__ O,
    const float* __restrict__ flng, const float* __restrict__ flnb,
    const float* __restrict__ w1W, const float* __restrict__ w1b,
    const float* __restrict__ w2W, const float* __restrict__ w2b,
    const float* __restrict__ alng, const float* __restrict__ alnb,
    const float* __restrict__ QW, const float* __restrict__ Qb,
    const float* __restrict__ KW, const float* __restrict__ Kb,
    const float* __restrict__ VW, const float* __restrict__ Vb,
    const float* __restrict__ posK, const float* __restrict__ posV,
    float* __restrict__ Q, float* __restrict__ K, float* __restrict__ V,
    const float* __restrict__ llng, const float* __restrict__ llnb,
    float* __restrict__ out, int nb, int last)
{
    int r0 = blockIdx.x * 2, t = threadIdx.x;
    __shared__ float ys[256], h1s[256], parts[256], pk[256], pv[256];
    __shared__ float wsum[8];
    ys[t] = Qn[r0 * 128 + t] + O[r0 * 128 + t];
    __syncthreads();
    int w_ = t >> 6, row = w_ >> 1, l = t & 63, ch = ((w_ & 1) << 6) + l;
    float x = ys[row * 128 + ch];
    float s1 = red64(x);
    if (l == 0) wsum[w_] = s1;
    __syncthreads();
    float mean = (wsum[row * 2] + wsum[row * 2 + 1]) * (1.f / 128.f);
    float dlt = x - mean;
    float s2 = red64(dlt * dlt);
    if (l == 0) wsum[4 + w_] = s2;
    __syncthreads();
    float rstd = rsqrtf((wsum[4 + row * 2] + wsum[4 + row * 2 + 1]) * (1.f / 128.f) + EPSF);
    float yv = dlt * rstd * flng[nb * 128 + ch] + flnb[nb * 128 + ch];
    __syncthreads();
    ys[row * 128 + ch] = yv;
    __syncthreads();

    int h = t & 127, kh = t >> 7;
    {
        const float4* w4p = (const float4*)(w1W + nb * 16384 + h * 128 + kh * 64);
        const float* y0 = ys + kh * 64;
        const float* y1 = ys + 128 + kh * 64;
        float a0 = 0.f, a1 = 0.f, b0 = 0.f, b1 = 0.f;
#pragma unroll 16
        for (int k4 = 0; k4 < 16; ++k4) {
            float4 w4 = w4p[k4];
            int k = k4 * 4;
            a0 += y0[k] * w4.x + y0[k + 1] * w4.y;
            a1 += y0[k + 2] * w4.z + y0[k + 3] * w4.w;
            b0 += y1[k] * w4.x + y1[k + 1] * w4.y;
            b1 += y1[k + 2] * w4.z + y1[k + 3] * w4.w;
        }
        float A0 = a0 + a1, A1 = b0 + b1;
        if (kh) { parts[h] = A0; parts[128 + h] = A1; }
        __syncthreads();
        if (!kh) {
            float v0 = A0 + parts[h] + w1b[nb * 128 + h];
            float v1 = A1 + parts[128 + h] + w1b[nb * 128 + h];
            h1s[h] = 0.5f * v0 * (1.f + erff(v0 * 0.70710678118654752f));
            h1s[128 + h] = 0.5f * v1 * (1.f + erff(v1 * 0.70710678118654752f));
        }
    }
    __syncthreads();
    {
        const float4* w4p = (const float4*)(w2W + nb * 16384 + h * 128 + kh * 64);
        const float* y0 = h1s + kh * 64;
        const float* y1 = h1s + 128 + kh * 64;
        float a0 = 0.f, a1 = 0.f, b0 = 0.f, b1 = 0.f;
#pragma unroll 16
        for (int k4 = 0; k4 < 16; ++k4) {
            float4 w4 = w4p[k4];
            int k = k4 * 4;
            a0 += y0[k] * w4.x + y0[k + 1] * w4.y;
            a1 += y0[k + 2] * w4.z + y0[k + 3] * w4.w;
            b0 += y1[k] * w4.x + y1[k + 1] * w4.y;
            b1 += y1[k + 2] * w4.z + y1[k + 3] * w4.w;
        }
        float A0 = a0 + a1, A1 = b0 + b1;
        __syncthreads();
        if (kh) { parts[h] = A0; parts[128 + h] = A1; }
        __syncthreads();
        if (!kh) {
            float z0 = A0 + parts[h] + w2b[nb * 128 + h] + ys[h];
            float z1 = A1 + parts[128 + h] + w2b[nb * 128 + h] + ys[128 + h];
            z0 = (ids[r0] == 0) ? 0.f : z0;
            z1 = (ids[r0 + 1] == 0) ? 0.f : z1;
            h1s[h] = z0; h1s[128 + h] = z1;
        }
    }
    __syncthreads();

    if (last) {
        x = h1s[row * 128 + ch];
        s1 = red64(x);
        if (l == 0) wsum[w_] = s1;
        __syncthreads();
        mean = (wsum[row * 2] + wsum[row * 2 + 1]) * (1.f / 128.f);
        dlt = x - mean;
        s2 = red64(dlt * dlt);
        if (l == 0) wsum[4 + w_] = s2;
        __syncthreads();
        rstd = rsqrtf((wsum[4 + row * 2] + wsum[4 + row * 2 + 1]) * (1.f / 128.f) + EPSF);
        out[(r0 + row) * 128 + ch] = dlt * rstd * llng[ch] + llnb[ch];
        return;
    }

    int nq = nb + 1;
    x = h1s[row * 128 + ch];
    s1 = red64(x);
    if (l == 0) wsum[w_] = s1;
    __syncthreads();
    mean = (wsum[row * 2] + wsum[row * 2 + 1]) * (1.f / 128.f);
    dlt = x - mean;
    s2 = red64(dlt * dlt);
    if (l == 0) wsum[4 + w_] = s2;
    __syncthreads();
    rstd = rsqrtf((wsum[4 + row * 2] + wsum[4 + row * 2 + 1]) * (1.f / 128.f) + EPSF);
    float qn = dlt * rstd * alng[nq * 128 + ch] + alnb[nq * 128 + ch];
    __syncthreads();
    ys[row * 128 + ch] = qn;
    Qn[(r0 + row) * 128 + ch] = qn;
    __syncthreads();

    {
        const float4* qw4 = (const float4*)(QW + nq * 16384 + h * 128 + kh * 64);
        const float4* kw4 = (const float4*)(KW + nq * 16384 + h * 128 + kh * 64);
        const float4* vw4 = (const float4*)(VW + nq * 16384 + h * 128 + kh * 64);
        const float* q0p = ys + kh * 64;
        const float* q1p = ys + 128 + kh * 64;
        const float* x0p = h1s + kh * 64;
        const float* x1p = h1s + 128 + kh * 64;
        float aq0 = 0, aq1 = 0, ak0 = 0, ak1 = 0, av0 = 0, av1 = 0;
#pragma unroll 8
        for (int k4 = 0; k4 < 16; ++k4) {
            float4 wq = qw4[k4], wk = kw4[k4], wv = vw4[k4];
            int k = k4 * 4;
            aq0 += q0p[k] * wq.x + q0p[k + 1] * wq.y + q0p[k + 2] * wq.z + q0p[k + 3] * wq.w;
            aq1 += q1p[k] * wq.x + q1p[k + 1] * wq.y + q1p[k + 2] * wq.z + q1p[k + 3] * wq.w;
            ak0 += x0p[k] * wk.x + x0p[k + 1] * wk.y + x0p[k + 2] * wk.z + x0p[k + 3] * wk.w;
            ak1 += x1p[k] * wk.x + x1p[k + 1] * wk.y + x1p[k + 2] * wk.z + x1p[k + 3] * wk.w;
            av0 += x0p[k] * wv.x + x0p[k + 1] * wv.y + x0p[k + 2] * wv.z + x0p[k + 3] * wv.w;
            av1 += x1p[k] * wv.x + x1p[k + 1] * wv.y + x1p[k + 2] * wv.z + x1p[k + 3] * wv.w;
        }
        if (kh) {
            parts[h] = aq0; parts[128 + h] = aq1;
            pk[h] = ak0; pk[128 + h] = ak1;
            pv[h] = av0; pv[128 + h] = av1;
        }
        __syncthreads();
        if (!kh) {
            int s0 = r0 & (Sn - 1), s1_ = (r0 + 1) & (Sn - 1);
            Q[r0 * 128 + h]       = aq0 + parts[h]       + Qb[nq * 128 + h];
            Q[(r0 + 1) * 128 + h] = aq1 + parts[128 + h] + Qb[nq * 128 + h];
            K[r0 * 128 + h]       = ak0 + pk[h]          + Kb[nq * 128 + h] + posK[s0 * 128 + h];
            K[(r0 + 1) * 128 + h] = ak1 + pk[128 + h]    + Kb[nq * 128 + h] + posK[s1_ * 128 + h];
            V[r0 * 128 + h]       = av0 + pv[h]          + Vb[nq * 128 + h] + posV[s0 * 128 + h];
            V[(r0 + 1) * 128 + h] = av1 + pv[128 + h]    + Vb[nq * 128 + h] + posV[s1_ * 128 + h];
        }
    }
}

// ---------------------------------------------------------------------------
extern "C" void kernel_launch(void* const* d_in, const int* in_sizes, int n_in,
                              void* d_out, int out_size, void* d_ws, size_t ws_size,
                              hipStream_t stream) {
    const int*   ids   = (const int*)  d_in[0];
    const float* meta  = (const float*)d_in[1];
    const int*   cats  = (const int*)  d_in[2];
    const int*   tmat  = (const int*)  d_in[3];
    const float* itemw = (const float*)d_in[4];
    const float* catw  = (const float*)d_in[5];
    const float* numW  = (const float*)d_in[6];
    const float* numb  = (const float*)d_in[7];
    const float* fusW  = (const float*)d_in[8];
    const float* fusb  = (const float*)d_in[9];
    const float* elng  = (const float*)d_in[10];
    const float* elnb  = (const float*)d_in[11];
    const float* posK  = (const float*)d_in[12];
    const float* posV  = (const float*)d_in[13];
    const float* tKw   = (const float*)d_in[14];
    const float* tVw   = (const float*)d_in[15];
    const float* alng  = (const float*)d_in[16];
    const float* alnb  = (const float*)d_in[17];
    const float* QW    = (const float*)d_in[18];
    const float* Qb    = (const float*)d_in[19];
    const float* KW    = (const float*)d_in[20];
    const float* Kb    = (const float*)d_in[21];
    const float* VW    = (const float*)d_in[22];
    const float* Vb    = (const float*)d_in[23];
    const float* flng  = (const float*)d_in[24];
    const float* flnb  = (const float*)d_in[25];
    const float* w1W   = (const float*)d_in[26];
    const float* w1b   = (const float*)d_in[27];
    const float* w2W   = (const float*)d_in[28];
    const float* w2b   = (const float*)d_in[29];
    const float* llng  = (const float*)d_in[30];
    const float* llnb  = (const float*)d_in[31];
    (void)in_sizes; (void)n_in; (void)out_size; (void)ws_size;

    float* ws = (float*)d_ws;
    float* Qn   = ws + OFF_QN;
    float* Q    = ws + OFF_Q;
    float* K    = ws + OFF_K;
    float* V    = ws + OFF_V;
    float* O    = ws + OFF_O;
    float* out  = (float*)d_out;

    embed_qkv_kernel<<<ROWS / 2, 256, 0, stream>>>(
        ids, meta, cats, itemw, catw, numW, numb, fusW, fusb, elng, elnb,
        alng, alnb, QW, Qb, KW, Kb, VW, Vb, posK, posV, Qn, Q, K, V);
    for (int nb = 0; nb < NBn; ++nb) {
        attn_kernel<<<512, 256, 0, stream>>>(ids, tmat, Q, K, V, tKw, tVw, O);
        ffn_qkv_kernel<<<ROWS / 2, 256, 0, stream>>>(
            ids, Qn, O, flng, flnb, w1W, w1b, w2W, w2b,
            alng, alnb, QW, Qb, KW, Kb, VW, Vb, posK, posV,
            Q, K, V, llng, llnb, out, nb, (nb == NBn - 1) ? 1 : 0);
    }
}